// Round 1
// baseline (21.252 us; speedup 1.0000x reference)
//
#include <hip/hip_runtime.h>

#define NS_TOL2  1e-12f
#define NS_MAXIT 50
#define NS_CMIN -1.0f
#define NS_CMAX  2.0f

__global__ __launch_bounds__(256) void newton_sor_kernel(
    const float* __restrict__ x,
    const float* __restrict__ omega,
    float* __restrict__ out, int B)
{
    int i = blockIdx.x * blockDim.x + threadIdx.x;
    if (i >= B) return;

    const float* xr = x + (size_t)i * 7;
    float y0o = xr[0], y1o = xr[1], y2o = xr[2];
    float h   = xr[3], k1  = xr[4], k2  = xr[5], k3 = xr[6];
    float om  = omega[i];

    // Loop-invariant algebra
    float hk1 = h * k1, hk2 = h * k2, hk3 = h * k3;
    float J00 = -hk1 - 1.0f;                      // constant Jacobian entry (<= -1, rcp safe)
    float rJ00 = __builtin_amdgcn_rcpf(J00);
    float omrJ00 = om * rJ00;                     // used for y0 update: y0 - om*dx0
    float omhk1  = om * hk1;                      // om * J10
    float hk2x2  = 2.0f * hk2;

    float y0 = y0o, y1 = y1o, y2 = y2o;

    // F at initial y
    float p = y1 * y2, q = y1 * y1;
    float f0 = fmaf(J00, y0, fmaf(hk3, p, y0o));
    float f1 = y1o + hk1 * y0 - hk2 * q - hk3 * p - y1;
    float f2 = fmaf(hk2, q, y2o - y2);

    for (int it = 0; it < NS_MAXIT; ++it) {
        float err2 = fmaf(f0, f0, fmaf(f1, f1, f2 * f2));
        if (__all(err2 <= NS_TOL2)) break;        // whole wave converged -> further
                                                  // reference updates are ~1e-6 no-ops

        float t   = hk2x2 * y1;                   // = J21 = 2*h*k2*y1
        float J11 = -(fmaf(hk3, y2, t)) - 1.0f;   // h*(-2k2*y1 - k3*y2) - 1

        float dx0  = f0 * rJ00;                   // F0 / J00
        float num1 = fmaf(-omhk1, dx0, f1);       // F1 - om*J10*dx0
        float dx1  = num1 * __builtin_amdgcn_rcpf(J11);
        float dx2  = fmaf(om * t, dx1, -f2);      // (F2 - om*J21*dx1)/(-1)

        float yn0 = fmaf(-omrJ00, f0, y0);        // y0 - om*dx0
        float yn1 = fmaf(-om, dx1, y1);
        float yn2 = fmaf(-om, dx2, y2);
        yn0 = fminf(fmaxf(yn0, NS_CMIN), NS_CMAX);
        yn1 = fminf(fmaxf(yn1, NS_CMIN), NS_CMAX);
        yn2 = fminf(fmaxf(yn2, NS_CMIN), NS_CMAX);
        y0 = yn0; y1 = yn1; y2 = yn2;

        p = y1 * y2; q = y1 * y1;
        f0 = fmaf(J00, y0, fmaf(hk3, p, y0o));
        f1 = y1o + hk1 * y0 - hk2 * q - hk3 * p - y1;
        f2 = fmaf(hk2, q, y2o - y2);
    }

    float* o = out + (size_t)i * 3;
    o[0] = y0; o[1] = y1; o[2] = y2;
}

extern "C" void kernel_launch(void* const* d_in, const int* in_sizes, int n_in,
                              void* d_out, int out_size, void* d_ws, size_t ws_size,
                              hipStream_t stream) {
    const float* x     = (const float*)d_in[0];
    const float* omega = (const float*)d_in[1];
    float* out = (float*)d_out;
    int B = in_sizes[0] / 7;

    int block = 256;
    int grid = (B + block - 1) / block;
    newton_sor_kernel<<<grid, block, 0, stream>>>(x, omega, out, B);
}